// Round 12
// baseline (203.281 us; speedup 1.0000x reference)
//
#include <hip/hip_runtime.h>
#include <hip/hip_bf16.h>

#define N_   16
#define P_   4096
#define C_   128
#define HW_  784
#define G_   512

typedef unsigned short u16;
typedef unsigned int   u32;
typedef __attribute__((ext_vector_type(8))) short bf16x8;
typedef __attribute__((ext_vector_type(4))) float f32x4;

union B8 { bf16x8 v; u32 w[4]; };

#define MFMA(a,b,c) __builtin_amdgcn_mfma_f32_16x16x32_bf16((a),(b),(c),0,0,0)

__device__ __forceinline__ u16 f2b(float f) {
    __hip_bfloat16 h = __float2bfloat16(f);
    return *reinterpret_cast<u16*>(&h);
}
__device__ __forceinline__ u32 pk(float lo, float hi) {
    return (u32)f2b(lo) | ((u32)f2b(hi) << 16);
}

// ---------------------------------------------------------------------------
// ws layout (bytes). bf16 A-operand matrices stored with M-dim rows PERMUTED
// so MFMA D-layout (row=4g+reg) lands in B-fragment k-order (k=8g+j):
//   row position (16ct + r) holds true idx 32*(ct>>1) + 8*(r>>2) + 4*(ct&1) + (r&3)
// ---------------------------------------------------------------------------
#define OFF_SW2P    0         // 800x128 bf16 (q rows permuted, q>=784 zero)
#define OFF_SW1P    204800    // 128x32 bf16 (out-c permuted, k>=15 zero)
#define OFF_GW1P    212992    // 128x32 bf16
#define OFF_GW2P    221184    // 128x128 bf16 (out-c permuted)
#define OFF_FW1BP   253952    // 128x128 bf16 (out-c permuted, fw1 rows 529+)
#define OFF_FW2P    286720    // 128x128 bf16 (out-c permuted)
#define OFF_SB2P    319488    // 800 f32 (plain order, q>=784 = -1e30)
#define OFF_GLOBGH  322688    // 16x128 f32
#define OFF_GLOBF1  330880    // 16x128 f32
#define OFF_FW1SP   339072    // 128x32 bf16 (perm rows; k<15 fw1[k], 15->527, 16->528, else 0)
#define OFF_FW3P    347264    // 128x4 f32 (perm rows of fw3, 4th = 0)
#define OFF_FILTP   349312    // 16x128x800 bf16 (c rows permuted, q>=784 zero)

// prep segment ends (flat thread index)
#define E0 102400   // sw2p  800*128
#define E1 110592   // sw1p  128*32
#define E2 118784   // gw1p  128*32
#define E3 135168   // gw2p  128*128
#define E4 151552   // fw1bp 128*128
#define E5 167936   // fw2p  128*128
#define E6 168736   // sb2p  800
#define E7 185120   // glob  2*16*128*4 (4-way k-split)
#define E8 189216   // fw1sp 128*32
#define E9 189728   // fw3p  128*4
#define E10 1828128 // filtp 16*128*800

__device__ __forceinline__ int perm_c(int row) {   // row pos -> true index
    const int ct = row >> 4, r = row & 15;
    return 32 * (ct >> 1) + 8 * (r >> 2) + 4 * (ct & 1) + (r & 3);
}

// ---------------------------------------------------------------------------
__global__ __launch_bounds__(256) void k_prep(
    const float* __restrict__ sw1, const float* __restrict__ sw2,
    const float* __restrict__ sb2, const float* __restrict__ gw1,
    const float* __restrict__ gw2, const float* __restrict__ fw1,
    const float* __restrict__ fw2, const float* __restrict__ fw3,
    const float* __restrict__ filters, const float* __restrict__ enc_glob,
    u16* __restrict__ sw2p, u16* __restrict__ sw1p, u16* __restrict__ gw1p,
    u16* __restrict__ gw2p, u16* __restrict__ fw1bp, u16* __restrict__ fw2p,
    float* __restrict__ sb2p, u16* __restrict__ fw1sp, float* __restrict__ fw3p,
    u16* __restrict__ filtp,
    float* __restrict__ glob_gh, float* __restrict__ glob_f1)
{
    const int idx = blockIdx.x * 256 + threadIdx.x;
    if (idx < E0) {                       // sw2p: q-rows permuted per 32-block
        const int r_new = idx >> 7, c = idx & 127;
        const int kt = r_new >> 5, o = r_new & 31, h = (o >> 4) & 1, r = o & 15;
        const int q = kt * 32 + 8 * (r >> 2) + 4 * h + (r & 3);
        sw2p[idx] = (q < HW_) ? f2b(sw2[c * HW_ + q]) : (u16)0;
    } else if (idx < E1) {                // sw1p
        const int t = idx - E0;
        const int row = t >> 5, k = t & 31;
        const int c = perm_c(row);
        sw1p[t] = (k < 15) ? f2b(sw1[k * C_ + c]) : (u16)0;
    } else if (idx < E2) {                // gw1p
        const int t = idx - E1;
        const int row = t >> 5, k = t & 31;
        const int c = perm_c(row);
        gw1p[t] = (k < 15) ? f2b(gw1[k * C_ + c]) : (u16)0;
    } else if (idx < E3) {                // gw2p
        const int t = idx - E2;
        const int row = t >> 7, ci = t & 127;
        gw2p[t] = f2b(gw2[ci * C_ + perm_c(row)]);
    } else if (idx < E4) {                // fw1bp (fw1 rows 529..656)
        const int t = idx - E3;
        const int row = t >> 7, ci = t & 127;
        fw1bp[t] = f2b(fw1[(529 + ci) * C_ + perm_c(row)]);
    } else if (idx < E5) {                // fw2p
        const int t = idx - E4;
        const int row = t >> 7, ci = t & 127;
        fw2p[t] = f2b(fw2[ci * C_ + perm_c(row)]);
    } else if (idx < E6) {                // sb2p: plain order + -inf tail
        const int q = idx - E5;
        sb2p[q] = (q < HW_) ? sb2[q] : -1e30f;
    } else if (idx < E7) {                // glob: 4 threads per output, k-split
        const int t = idx - E6;           // 0..16383
        const int sub = t & 3, r = t >> 2;
        const int which = r >> 11, nn = (r >> 7) & 15, c = r & 127;
        const float* W = which ? fw1 : gw1;
        const float* gv = enc_glob + nn * G_ + sub * 128;
        const float* Wp = W + (15 + sub * 128) * C_ + c;
        float acc = 0.f;
        for (int k = 0; k < 128; ++k) acc += gv[k] * Wp[k * C_];
        acc += __shfl_xor(acc, 1);
        acc += __shfl_xor(acc, 2);
        if (sub == 0) (which ? glob_f1 : glob_gh)[nn * C_ + c] = acc;
    } else if (idx < E8) {                // fw1sp: x/coord side-weights
        const int t = idx - E7;
        const int row = t >> 5, k = t & 31;
        const int c = perm_c(row);
        float v = 0.f;
        if (k < 15)       v = fw1[k * C_ + c];
        else if (k == 15) v = fw1[527 * C_ + c];
        else if (k == 16) v = fw1[528 * C_ + c];
        fw1sp[t] = f2b(v);
    } else if (idx < E9) {                // fw3p: perm rows of fw3, padded
        const int t = idx - E8;
        const int row = t >> 2, j = t & 3;
        fw3p[t] = (j < 3) ? fw3[perm_c(row) * 3 + j] : 0.f;
    } else if (idx < E10) {               // filtp: bf16, perm c-rows, q padded
        const int t = idx - E9;
        const int nn = t / 102400;
        const int rr = t % 102400;
        const int row = rr / 800, q = rr % 800;
        const int c = perm_c(row);
        filtp[t] = (q < HW_) ? f2b(filters[((size_t)nn * C_ + c) * HW_ + q]) : (u16)0;
    }
}

// ---------------------------------------------------------------------------
// Main kernel: 64 points/block, 4 waves, 16 points/wave, grid 1024.
// Round-12 change: halved the per-wave tile (f dimension removed) to cut the
// unified register live set to ~105 so __launch_bounds__(256,4) fits
// 4 waves/SIMD = 4 blocks/CU (round-11 counters: 2 waves/SIMD left ~55% of
// cycles as uncovered latency). LDS 39.9 KB x 4 blocks = 159.7 KB/CU (fits).
// WRITE_SIZE is the spill tripwire (round-7 lesson).
// ---------------------------------------------------------------------------
__global__ __launch_bounds__(256, 4) void k_mfma(
    const float* __restrict__ points, const float* __restrict__ transform,
    const float* __restrict__ sb1, const float* __restrict__ gb1,
    const float* __restrict__ gb2, const float* __restrict__ fb1,
    const float* __restrict__ fb2, const float* __restrict__ fb3,
    const u16* __restrict__ sw1p, const u16* __restrict__ gw1p,
    const u16* __restrict__ sw2p, const float* __restrict__ sb2p,
    const u16* __restrict__ gw2p, const u16* __restrict__ fw1bp,
    const u16* __restrict__ fw2p, const u16* __restrict__ fw1sp,
    const float* __restrict__ fw3p, const u16* __restrict__ filtp,
    const float* __restrict__ glob_gh, const float* __restrict__ glob_f1,
    float* __restrict__ out)
{
    __shared__ __align__(16) float s_x[4][16][16];   // 4 KB
    __shared__ __align__(16) u16 s_w[2][32][136];    // 17408 B (pad: ~2-way)
    __shared__ __align__(16) u16 s_f[2][128][36];    // 18432 B (pad: spread)

    const int tid = threadIdx.x, wid = tid >> 6, lane = tid & 63;
    const int p = lane & 15, g = lane >> 4;
    // XCD swizzle: 1024 blocks, 128-chunk per XCD -> 2 distinct n per XCD L2.
    const int bid = blockIdx.x;
    const int nb  = (bid & 7) * 128 + (bid >> 3);
    const int n   = nb >> 6;
    const int pw  = ((nb & 63) << 6) + (wid << 4);

    const u16* filtn = filtp + (size_t)n * 102400;
    // staging slot coords (fixed per thread)
    const int swrow = tid >> 4, swc = tid & 15;   // sw2p rows swrow/+16, 16B col swc
    const int frp   = tid >> 2, fc16 = tid & 3;   // filt rows frp/+64, 16B col fc16

    // ---- A1: inputs to LDS (per-wave, 16 points) -------------------------
    for (int i = lane; i < 256; i += 64) {
        const int pt = i >> 4, k = i & 15;
        const int gp = n * P_ + pw + pt;
        float v = 0.f;
        if (k < 3)       v = points[gp * 3 + k];
        else if (k < 15) v = transform[gp * 12 + k - 3];
        s_x[wid][pt][k] = v;
    }

    // ---- stage chunk kt=0 into buffer 0 ----------------------------------
    {
        const bf16x8 w0 = *(const bf16x8*)(sw2p + (size_t)swrow * C_ + swc * 8);
        const bf16x8 w1 = *(const bf16x8*)(sw2p + (size_t)(16 + swrow) * C_ + swc * 8);
        const bf16x8 f0 = *(const bf16x8*)(filtn + (size_t)frp * 800 + fc16 * 8);
        const bf16x8 f1 = *(const bf16x8*)(filtn + (size_t)(64 + frp) * 800 + fc16 * 8);
        *(bf16x8*)&s_w[0][swrow][swc * 8]      = w0;
        *(bf16x8*)&s_w[0][16 + swrow][swc * 8] = w1;
        *(bf16x8*)&s_f[0][frp][fc16 * 8]       = f0;
        *(bf16x8*)&s_f[0][64 + frp][fc16 * 8]  = f1;
    }
    __syncthreads();

    // ---- bxc: [x(15), cx, cy, 0...] as B-fragment (k = 8g+j) -------------
    B8 bxc;
    bxc.w[0] = bxc.w[1] = bxc.w[2] = bxc.w[3] = 0u;
    {
        const float* xs = &s_x[wid][p][0];
        const int pp = pw + p;
        const float cx = -1.f + 2.f * (float)(pp >> 6) / 63.f;
        const float cy = -1.f + 2.f * (float)(pp & 63) / 63.f;
        if (g == 0) {
            bxc.w[0] = pk(xs[0], xs[1]);  bxc.w[1] = pk(xs[2], xs[3]);
            bxc.w[2] = pk(xs[4], xs[5]);  bxc.w[3] = pk(xs[6], xs[7]);
        } else if (g == 1) {
            bxc.w[0] = pk(xs[8], xs[9]);  bxc.w[1] = pk(xs[10], xs[11]);
            bxc.w[2] = pk(xs[12], xs[13]); bxc.w[3] = pk(xs[14], cx);
        } else if (g == 2) {
            bxc.w[0] = pk(cy, 0.f);
        }
    }

    // ---- A2: sh via MFMA -------------------------------------------------
    B8 bsh[4];
    #pragma unroll
    for (int ct = 0; ct < 8; ++ct) {
        const bf16x8 a_s = *(const bf16x8*)(sw1p + (16 * ct + p) * 32 + 8 * g);
        const int cb = 32 * (ct >> 1) + 8 * g + 4 * (ct & 1);
        const f32x4 b1 = *(const f32x4*)(sb1 + cb);
        const int m = ct >> 1, o = (ct & 1) * 2;
        f32x4 cs = (f32x4){0.f, 0.f, 0.f, 0.f};
        cs = MFMA(a_s, bxc.v, cs);
        const float s0 = fmaxf(cs[0] + b1[0], 0.f), s1 = fmaxf(cs[1] + b1[1], 0.f);
        const float s2 = fmaxf(cs[2] + b1[2], 0.f), s3 = fmaxf(cs[3] + b1[3], 0.f);
        bsh[m].w[o] = pk(s0, s1); bsh[m].w[o + 1] = pk(s2, s3);
    }

    // ---- B: kt loop, double-buffered LDS ---------------------------------
    f32x4 pv[8];
    #pragma unroll
    for (int ct = 0; ct < 8; ++ct) pv[ct] = (f32x4){0.f, 0.f, 0.f, 0.f};
    float psum = 0.f;

    for (int kt = 0; kt < 25; ++kt) {
        const int cur = kt & 1, nxt = cur ^ 1;
        // -- T14: issue next chunk's global loads first --
        bf16x8 stw0, stw1, stf0, stf1;
        if (kt < 24) {
            const int q0 = 32 * (kt + 1);
            stw0 = *(const bf16x8*)(sw2p + (size_t)(q0 + swrow) * C_ + swc * 8);
            stw1 = *(const bf16x8*)(sw2p + (size_t)(q0 + 16 + swrow) * C_ + swc * 8);
            stf0 = *(const bf16x8*)(filtn + (size_t)frp * 800 + q0 + fc16 * 8);
            stf1 = *(const bf16x8*)(filtn + (size_t)(64 + frp) * 800 + q0 + fc16 * 8);
        }

        // -- compute current chunk from LDS --
        B8 bq;
        #pragma unroll
        for (int h = 0; h < 2; ++h) {
            const u16* wr = &s_w[cur][16 * h + p][8 * g];
            const bf16x8 aw0 = *(const bf16x8*)(wr);
            const bf16x8 aw1 = *(const bf16x8*)(wr + 32);
            const bf16x8 aw2 = *(const bf16x8*)(wr + 64);
            const bf16x8 aw3 = *(const bf16x8*)(wr + 96);
            const f32x4 bi = *(const f32x4*)(sb2p + 32 * kt + 8 * g + 4 * h);
            f32x4 c4 = (f32x4){0.f, 0.f, 0.f, 0.f};
            c4 = MFMA(aw0, bsh[0].v, c4);
            c4 = MFMA(aw1, bsh[1].v, c4);
            c4 = MFMA(aw2, bsh[2].v, c4);
            c4 = MFMA(aw3, bsh[3].v, c4);
            const float e0 = __expf(fminf(c4[0] + bi[0], 60.f));
            const float e1 = __expf(fminf(c4[1] + bi[1], 60.f));
            const float e2 = __expf(fminf(c4[2] + bi[2], 60.f));
            const float e3 = __expf(fminf(c4[3] + bi[3], 60.f));
            psum += (e0 + e1) + (e2 + e3);
            bq.w[2 * h + 0] = pk(e0, e1);
            bq.w[2 * h + 1] = pk(e2, e3);
        }
        #pragma unroll
        for (int ct = 0; ct < 8; ++ct) {
            const bf16x8 af = *(const bf16x8*)&s_f[cur][16 * ct + p][8 * g];
            pv[ct] = MFMA(af, bq.v, pv[ct]);
        }

        // -- write staged data into the other buffer --
        if (kt < 24) {
            *(bf16x8*)&s_w[nxt][swrow][swc * 8]      = stw0;
            *(bf16x8*)&s_w[nxt][16 + swrow][swc * 8] = stw1;
            *(bf16x8*)&s_f[nxt][frp][fc16 * 8]       = stf0;
            *(bf16x8*)&s_f[nxt][64 + frp][fc16 * 8]  = stf1;
        }
        __syncthreads();
    }
    psum += __shfl_xor(psum, 16);
    psum += __shfl_xor(psum, 32);
    const float inv = 1.f / psum;

    // ---- C-pre: gh via MFMA (from bxc; k>=15 weight rows zero) -----------
    B8 bgh[4];
    #pragma unroll
    for (int ct = 0; ct < 8; ++ct) {
        const bf16x8 a_g = *(const bf16x8*)(gw1p + (16 * ct + p) * 32 + 8 * g);
        const int cb = 32 * (ct >> 1) + 8 * g + 4 * (ct & 1);
        const f32x4 b2 = *(const f32x4*)(gb1 + cb);
        const f32x4 gg = *(const f32x4*)(glob_gh + n * C_ + cb);
        const int m = ct >> 1, o = (ct & 1) * 2;
        f32x4 cg = (f32x4){0.f, 0.f, 0.f, 0.f};
        cg = MFMA(a_g, bxc.v, cg);
        const float g0 = fmaxf(cg[0] + b2[0] + gg[0], 0.f), g1 = fmaxf(cg[1] + b2[1] + gg[1], 0.f);
        const float g2 = fmaxf(cg[2] + b2[2] + gg[2], 0.f), g3 = fmaxf(cg[3] + b2[3] + gg[3], 0.f);
        bgh[m].w[o] = pk(g0, g1); bgh[m].w[o + 1] = pk(g2, g3);
    }

    // ---- C: gattn = sigmoid(gw2.gh + gb2); sf = gattn * pv * inv ---------
    B8 bsf[4];
    #pragma unroll
    for (int ct = 0; ct < 8; ++ct) {
        const u16* ar = gw2p + (16 * ct + p) * C_ + 8 * g;
        f32x4 acc = (f32x4){0.f, 0.f, 0.f, 0.f};
        acc = MFMA(*(const bf16x8*)(ar),      bgh[0].v, acc);
        acc = MFMA(*(const bf16x8*)(ar + 32), bgh[1].v, acc);
        acc = MFMA(*(const bf16x8*)(ar + 64), bgh[2].v, acc);
        acc = MFMA(*(const bf16x8*)(ar + 96), bgh[3].v, acc);
        const int cb = 32 * (ct >> 1) + 8 * g + 4 * (ct & 1);
        const f32x4 gb = *(const f32x4*)(gb2 + cb);
        const float s0 = pv[ct][0] * inv / (1.f + __expf(-(acc[0] + gb[0])));
        const float s1 = pv[ct][1] * inv / (1.f + __expf(-(acc[1] + gb[1])));
        const float s2 = pv[ct][2] * inv / (1.f + __expf(-(acc[2] + gb[2])));
        const float s3 = pv[ct][3] * inv / (1.f + __expf(-(acc[3] + gb[3])));
        const int m = ct >> 1, o = (ct & 1) * 2;
        bsf[m].w[o] = pk(s0, s1); bsf[m].w[o + 1] = pk(s2, s3);
    }

    // ---- D: h1 = relu(fw1b.sf + fw1s.[x,cx,cy] + glob + fb1) -------------
    B8 bh1[4];
    #pragma unroll
    for (int ct = 0; ct < 8; ++ct) {
        const u16* ar = fw1bp + (16 * ct + p) * C_ + 8 * g;
        const bf16x8 a_s = *(const bf16x8*)(fw1sp + (16 * ct + p) * 32 + 8 * g);
        f32x4 acc = (f32x4){0.f, 0.f, 0.f, 0.f};
        acc = MFMA(*(const bf16x8*)(ar),      bsf[0].v, acc);
        acc = MFMA(*(const bf16x8*)(ar + 32), bsf[1].v, acc);
        acc = MFMA(*(const bf16x8*)(ar + 64), bsf[2].v, acc);
        acc = MFMA(*(const bf16x8*)(ar + 96), bsf[3].v, acc);
        acc = MFMA(a_s, bxc.v, acc);         // x/coord side-term
        const int cb = 32 * (ct >> 1) + 8 * g + 4 * (ct & 1);
        const f32x4 fbv = *(const f32x4*)(fb1 + cb);
        const f32x4 gf  = *(const f32x4*)(glob_f1 + n * C_ + cb);
        const float h0 = fmaxf(acc[0] + fbv[0] + gf[0], 0.f);
        const float h1v = fmaxf(acc[1] + fbv[1] + gf[1], 0.f);
        const float h2 = fmaxf(acc[2] + fbv[2] + gf[2], 0.f);
        const float h3 = fmaxf(acc[3] + fbv[3] + gf[3], 0.f);
        const int m = ct >> 1, o = (ct & 1) * 2;
        bh1[m].w[o] = pk(h0, h1v); bh1[m].w[o + 1] = pk(h2, h3);
    }

    // ---- E+F fused: h2 = relu(fw2.h1 + fb2); d += h2 * fw3 ---------------
    float d0 = 0.f, d1 = 0.f, d2 = 0.f;
    #pragma unroll
    for (int ct = 0; ct < 8; ++ct) {
        const u16* ar = fw2p + (16 * ct + p) * C_ + 8 * g;
        f32x4 acc = (f32x4){0.f, 0.f, 0.f, 0.f};
        acc = MFMA(*(const bf16x8*)(ar),      bh1[0].v, acc);
        acc = MFMA(*(const bf16x8*)(ar + 32), bh1[1].v, acc);
        acc = MFMA(*(const bf16x8*)(ar + 64), bh1[2].v, acc);
        acc = MFMA(*(const bf16x8*)(ar + 96), bh1[3].v, acc);
        const int cb = 32 * (ct >> 1) + 8 * g + 4 * (ct & 1);
        const f32x4 o4 = *(const f32x4*)(fb2 + cb);
        #pragma unroll
        for (int r = 0; r < 4; ++r) {
            const float h = fmaxf(acc[r] + o4[r], 0.f);
            const f32x4 w3 = *(const f32x4*)(fw3p + (16 * ct + 4 * g + r) * 4);
            d0 += h * w3[0]; d1 += h * w3[1]; d2 += h * w3[2];
        }
    }
    d0 += __shfl_xor(d0, 16); d0 += __shfl_xor(d0, 32);
    d1 += __shfl_xor(d1, 16); d1 += __shfl_xor(d1, 32);
    d2 += __shfl_xor(d2, 16); d2 += __shfl_xor(d2, 32);
    if (g == 0) {
        const int gp = n * P_ + pw + p;
        out[gp * 3 + 0] = d0 + fb3[0] + s_x[wid][p][0];
        out[gp * 3 + 1] = d1 + fb3[1] + s_x[wid][p][1];
        out[gp * 3 + 2] = d2 + fb3[2] + s_x[wid][p][2];
    }
}

// ---------------------------------------------------------------------------
// Per-batch normalize in place (f32), 1024 threads.
// ---------------------------------------------------------------------------
__global__ __launch_bounds__(1024) void k_norm(float* __restrict__ out)
{
    __shared__ float red[48];
    __shared__ float red2[16];
    const int n = blockIdx.x, tid = threadIdx.x;
    float* pb = out + (size_t)n * P_ * 3;

    float sx = 0.f, sy = 0.f, sz = 0.f;
    for (int i = tid; i < P_; i += 1024) {
        sx += pb[i * 3 + 0]; sy += pb[i * 3 + 1]; sz += pb[i * 3 + 2];
    }
    #pragma unroll
    for (int m = 32; m >= 1; m >>= 1) {
        sx += __shfl_xor(sx, m); sy += __shfl_xor(sy, m); sz += __shfl_xor(sz, m);
    }
    const int wv = tid >> 6, ln = tid & 63;
    if (ln == 0) { red[wv * 3 + 0] = sx; red[wv * 3 + 1] = sy; red[wv * 3 + 2] = sz; }
    __syncthreads();
    float meanx = 0.f, meany = 0.f, meanz = 0.f;
    #pragma unroll
    for (int w = 0; w < 16; ++w) {
        meanx += red[w * 3 + 0]; meany += red[w * 3 + 1]; meanz += red[w * 3 + 2];
    }
    meanx /= (float)P_; meany /= (float)P_; meanz /= (float)P_;

    float mm = 0.f;
    for (int i = tid; i < P_; i += 1024) {
        const float dx = pb[i * 3 + 0] - meanx;
        const float dy = pb[i * 3 + 1] - meany;
        const float dz = pb[i * 3 + 2] - meanz;
        mm = fmaxf(mm, dx * dx + dy * dy + dz * dz);
    }
    #pragma unroll
    for (int m = 32; m >= 1; m >>= 1) mm = fmaxf(mm, __shfl_xor(mm, m));
    if (ln == 0) red2[wv] = mm;
    __syncthreads();
    mm = 0.f;
    #pragma unroll
    for (int w = 0; w < 16; ++w) mm = fmaxf(mm, red2[w]);
    const float scale = 1.f / (sqrtf(mm) + 1e-8f);

    for (int i = tid; i < P_; i += 1024) {
        pb[i * 3 + 0] = (pb[i * 3 + 0] - meanx) * scale;
        pb[i * 3 + 1] = (pb[i * 3 + 1] - meany) * scale;
        pb[i * 3 + 2] = (pb[i * 3 + 2] - meanz) * scale;
    }
}

// ---------------------------------------------------------------------------
extern "C" void kernel_launch(void* const* d_in, const int* in_sizes, int n_in,
                              void* d_out, int out_size, void* d_ws, size_t ws_size,
                              hipStream_t stream) {
    const float* points    = (const float*)d_in[0];
    const float* transform = (const float*)d_in[1];
    const float* filters   = (const float*)d_in[2];
    const float* enc_glob  = (const float*)d_in[3];
    const float* sw1 = (const float*)d_in[4];
    const float* sb1 = (const float*)d_in[5];
    const float* sw2 = (const float*)d_in[6];
    const float* sb2 = (const float*)d_in[7];
    const float* gw1 = (const float*)d_in[8];
    const float* gb1 = (const float*)d_in[9];
    const float* gw2 = (const float*)d_in[10];
    const float* gb2 = (const float*)d_in[11];
    const float* fw1 = (const float*)d_in[12];
    const float* fb1 = (const float*)d_in[13];
    const float* fw2 = (const float*)d_in[14];
    const float* fb2 = (const float*)d_in[15];
    const float* fw3 = (const float*)d_in[16];
    const float* fb3 = (const float*)d_in[17];

    char* ws = (char*)d_ws;
    u16*   sw2p    = (u16*)(ws + OFF_SW2P);
    u16*   sw1p    = (u16*)(ws + OFF_SW1P);
    u16*   gw1p    = (u16*)(ws + OFF_GW1P);
    u16*   gw2p    = (u16*)(ws + OFF_GW2P);
    u16*   fw1bp   = (u16*)(ws + OFF_FW1BP);
    u16*   fw2p    = (u16*)(ws + OFF_FW2P);
    float* sb2p    = (float*)(ws + OFF_SB2P);
    float* glob_gh = (float*)(ws + OFF_GLOBGH);
    float* glob_f1 = (float*)(ws + OFF_GLOBF1);
    u16*   fw1sp   = (u16*)(ws + OFF_FW1SP);
    float* fw3p    = (float*)(ws + OFF_FW3P);
    u16*   filtp   = (u16*)(ws + OFF_FILTP);
    float* out     = (float*)d_out;

    k_prep<<<(E10 + 255) / 256, 256, 0, stream>>>(
        sw1, sw2, sb2, gw1, gw2, fw1, fw2, fw3, filters, enc_glob,
        sw2p, sw1p, gw1p, gw2p, fw1bp, fw2p, sb2p, fw1sp, fw3p, filtp,
        glob_gh, glob_f1);
    k_mfma<<<N_ * (P_ / 64), 256, 0, stream>>>(
        points, transform, sb1, gb1, gb2, fb1, fb2, fb3,
        sw1p, gw1p, sw2p, sb2p, gw2p, fw1bp, fw2p, fw1sp, fw3p, filtp,
        glob_gh, glob_f1, out);
    k_norm<<<N_, 1024, 0, stream>>>(out);
}

// Round 13
// 182.256 us; speedup vs baseline: 1.1154x; 1.1154x over previous
//
#include <hip/hip_runtime.h>
#include <hip/hip_bf16.h>

#define N_   16
#define P_   4096
#define C_   128
#define HW_  784
#define G_   512

typedef unsigned short u16;
typedef unsigned int   u32;
typedef __attribute__((ext_vector_type(8))) short bf16x8;
typedef __attribute__((ext_vector_type(4))) float f32x4;

union B8 { bf16x8 v; u32 w[4]; };

#define MFMA(a,b,c) __builtin_amdgcn_mfma_f32_16x16x32_bf16((a),(b),(c),0,0,0)

__device__ __forceinline__ u16 f2b(float f) {
    __hip_bfloat16 h = __float2bfloat16(f);
    return *reinterpret_cast<u16*>(&h);
}
__device__ __forceinline__ u32 pk(float lo, float hi) {
    return (u32)f2b(lo) | ((u32)f2b(hi) << 16);
}

// ---------------------------------------------------------------------------
// ws layout (bytes). bf16 A-operand matrices stored with M-dim rows PERMUTED
// so MFMA D-layout (row=4g+reg) lands in B-fragment k-order (k=8g+j):
//   row position (16ct + r) holds true idx 32*(ct>>1) + 8*(r>>2) + 4*(ct&1) + (r&3)
// ---------------------------------------------------------------------------
#define OFF_SW2P    0         // 800x128 bf16 (q rows permuted, q>=784 zero)
#define OFF_SW1P    204800    // 128x32 bf16 (out-c permuted, k>=15 zero)
#define OFF_GW1P    212992    // 128x32 bf16
#define OFF_GW2P    221184    // 128x128 bf16 (out-c permuted)
#define OFF_FW1BP   253952    // 128x128 bf16 (out-c permuted, fw1 rows 529+)
#define OFF_FW2P    286720    // 128x128 bf16 (out-c permuted)
#define OFF_SB2P    319488    // 800 f32 (plain order, q>=784 = -1e30)
#define OFF_GLOBGH  322688    // 16x128 f32
#define OFF_GLOBF1  330880    // 16x128 f32
#define OFF_FW1SP   339072    // 128x32 bf16 (perm rows; k<15 fw1[k], 15->527, 16->528, else 0)
#define OFF_FW3P    347264    // 128x4 f32 (perm rows of fw3, 4th = 0)
#define OFF_FILTP   349312    // 16x128x800 bf16 (c rows permuted, q>=784 zero)

// prep segment ends (flat thread index)
#define E0 102400   // sw2p  800*128
#define E1 110592   // sw1p  128*32
#define E2 118784   // gw1p  128*32
#define E3 135168   // gw2p  128*128
#define E4 151552   // fw1bp 128*128
#define E5 167936   // fw2p  128*128
#define E6 168736   // sb2p  800
#define E7 185120   // glob  2*16*128*4 (4-way k-split)
#define E8 189216   // fw1sp 128*32
#define E9 189728   // fw3p  128*4
#define E10 599328  // filtp 16*128*200 (4 elems per thread, 784%4==0)

__device__ __forceinline__ int perm_c(int row) {   // row pos -> true index
    const int ct = row >> 4, r = row & 15;
    return 32 * (ct >> 1) + 8 * (r >> 2) + 4 * (ct & 1) + (r & 3);
}

// ---------------------------------------------------------------------------
__global__ __launch_bounds__(256) void k_prep(
    const float* __restrict__ sw1, const float* __restrict__ sw2,
    const float* __restrict__ sb2, const float* __restrict__ gw1,
    const float* __restrict__ gw2, const float* __restrict__ fw1,
    const float* __restrict__ fw2, const float* __restrict__ fw3,
    const float* __restrict__ filters, const float* __restrict__ enc_glob,
    u16* __restrict__ sw2p, u16* __restrict__ sw1p, u16* __restrict__ gw1p,
    u16* __restrict__ gw2p, u16* __restrict__ fw1bp, u16* __restrict__ fw2p,
    float* __restrict__ sb2p, u16* __restrict__ fw1sp, float* __restrict__ fw3p,
    u16* __restrict__ filtp,
    float* __restrict__ glob_gh, float* __restrict__ glob_f1)
{
    const int idx = blockIdx.x * 256 + threadIdx.x;
    if (idx < E0) {                       // sw2p: q-rows permuted per 32-block
        const int r_new = idx >> 7, c = idx & 127;
        const int kt = r_new >> 5, o = r_new & 31, h = (o >> 4) & 1, r = o & 15;
        const int q = kt * 32 + 8 * (r >> 2) + 4 * h + (r & 3);
        sw2p[idx] = (q < HW_) ? f2b(sw2[c * HW_ + q]) : (u16)0;
    } else if (idx < E1) {                // sw1p
        const int t = idx - E0;
        const int row = t >> 5, k = t & 31;
        const int c = perm_c(row);
        sw1p[t] = (k < 15) ? f2b(sw1[k * C_ + c]) : (u16)0;
    } else if (idx < E2) {                // gw1p
        const int t = idx - E1;
        const int row = t >> 5, k = t & 31;
        const int c = perm_c(row);
        gw1p[t] = (k < 15) ? f2b(gw1[k * C_ + c]) : (u16)0;
    } else if (idx < E3) {                // gw2p
        const int t = idx - E2;
        const int row = t >> 7, ci = t & 127;
        gw2p[t] = f2b(gw2[ci * C_ + perm_c(row)]);
    } else if (idx < E4) {                // fw1bp (fw1 rows 529..656)
        const int t = idx - E3;
        const int row = t >> 7, ci = t & 127;
        fw1bp[t] = f2b(fw1[(529 + ci) * C_ + perm_c(row)]);
    } else if (idx < E5) {                // fw2p
        const int t = idx - E4;
        const int row = t >> 7, ci = t & 127;
        fw2p[t] = f2b(fw2[ci * C_ + perm_c(row)]);
    } else if (idx < E6) {                // sb2p: plain order + -inf tail
        const int q = idx - E5;
        sb2p[q] = (q < HW_) ? sb2[q] : -1e30f;
    } else if (idx < E7) {                // glob: 4 threads per output, k-split
        const int t = idx - E6;           // 0..16383
        const int sub = t & 3, r = t >> 2;
        const int which = r >> 11, nn = (r >> 7) & 15, c = r & 127;
        const float* W = which ? fw1 : gw1;
        const float* gv = enc_glob + nn * G_ + sub * 128;
        const float* Wp = W + (15 + sub * 128) * C_ + c;
        float acc = 0.f;
        for (int k = 0; k < 128; ++k) acc += gv[k] * Wp[k * C_];
        acc += __shfl_xor(acc, 1);
        acc += __shfl_xor(acc, 2);
        if (sub == 0) (which ? glob_f1 : glob_gh)[nn * C_ + c] = acc;
    } else if (idx < E8) {                // fw1sp: x/coord side-weights
        const int t = idx - E7;
        const int row = t >> 5, k = t & 31;
        const int c = perm_c(row);
        float v = 0.f;
        if (k < 15)       v = fw1[k * C_ + c];
        else if (k == 15) v = fw1[527 * C_ + c];
        else if (k == 16) v = fw1[528 * C_ + c];
        fw1sp[t] = f2b(v);
    } else if (idx < E9) {                // fw3p: perm rows of fw3, padded
        const int t = idx - E8;
        const int row = t >> 2, j = t & 3;
        fw3p[t] = (j < 3) ? fw3[perm_c(row) * 3 + j] : 0.f;
    } else if (idx < E10) {               // filtp: 4 elems/thread (784%4==0)
        const int t = idx - E9;
        const int nn = t / 25600;
        const int rr = t % 25600;
        const int row = rr / 200, qg = rr % 200;
        const int q0 = qg * 4;
        const int c = perm_c(row);
        u32 lo = 0u, hi = 0u;
        if (q0 < HW_) {                   // full in-bounds vec4 (q0 <= 780)
            const f32x4 v = *(const f32x4*)(filters + ((size_t)nn * C_ + c) * HW_ + q0);
            lo = pk(v[0], v[1]); hi = pk(v[2], v[3]);
        }
        const size_t base = (size_t)nn * 102400 + (size_t)row * 800 + q0;
        *(uint2*)(filtp + base) = make_uint2(lo, hi);
    }
}

// ---------------------------------------------------------------------------
// Main kernel: 256 points/block, 8 waves (512 threads), 32 points/wave.
// Round-13 change: DOUBLED the block (same per-wave tile as round 11) to
// halve aggregate staging traffic: staging is per-block-constant (16 KB per
// 32-q chunk), so 256 blocks x 25 chunks x 16 KB = 200 MB from L2 vs round
// 11's 800 MB / round 12's 1.6 GB (round-12 regression isolated staging L2
// bandwidth as the binding cost, NOT occupancy: 43% occ was slower).
// Grid 256 = exactly 1 block/CU; 2 waves/SIMD via __launch_bounds__(512,2)
// (round-11 live set ~184 unified fits the 256 cap; WRITE_SIZE = tripwire).
// ---------------------------------------------------------------------------
__global__ __launch_bounds__(512, 2) void k_mfma(
    const float* __restrict__ points, const float* __restrict__ transform,
    const float* __restrict__ sb1, const float* __restrict__ gb1,
    const float* __restrict__ gb2, const float* __restrict__ fb1,
    const float* __restrict__ fb2, const float* __restrict__ fb3,
    const u16* __restrict__ sw1p, const u16* __restrict__ gw1p,
    const u16* __restrict__ sw2p, const float* __restrict__ sb2p,
    const u16* __restrict__ gw2p, const u16* __restrict__ fw1bp,
    const u16* __restrict__ fw2p, const u16* __restrict__ fw1sp,
    const float* __restrict__ fw3p, const u16* __restrict__ filtp,
    const float* __restrict__ glob_gh, const float* __restrict__ glob_f1,
    float* __restrict__ out)
{
    __shared__ __align__(16) float s_x[8][32][16];   // 16 KB
    __shared__ __align__(16) u16 s_w[2][32][136];    // 17408 B
    __shared__ __align__(16) u16 s_f[2][128][36];    // 18432 B  (total 51.8 KB)

    const int tid = threadIdx.x, wid = tid >> 6, lane = tid & 63;
    const int p = lane & 15, g = lane >> 4;
    // XCD swizzle: 256 blocks, 32-chunk per XCD -> 2 distinct n per XCD L2.
    const int bid = blockIdx.x;
    const int nb  = (bid & 7) * 32 + (bid >> 3);
    const int n   = nb >> 4;
    const int pw  = ((nb & 15) << 8) + (wid << 5);

    const u16* filtn = filtp + (size_t)n * 102400;
    // staging slot coords (fixed per thread; 512 threads -> ONE b128 each)
    const int swrow = tid >> 4, swc = tid & 15;   // sw2p row 0..31, 16B col
    const int frp   = tid >> 2, fc16 = tid & 3;   // filt row 0..127, 16B col

    // ---- A1: inputs to LDS (per-wave, 32 points) -------------------------
    for (int i = lane; i < 512; i += 64) {
        const int pt = i >> 4, k = i & 15;
        const int gp = n * P_ + pw + pt;
        float v = 0.f;
        if (k < 3)       v = points[gp * 3 + k];
        else if (k < 15) v = transform[gp * 12 + k - 3];
        s_x[wid][pt][k] = v;
    }

    // ---- stage chunk kt=0 into buffer 0 ----------------------------------
    {
        const bf16x8 w0 = *(const bf16x8*)(sw2p + (size_t)swrow * C_ + swc * 8);
        const bf16x8 f0 = *(const bf16x8*)(filtn + (size_t)frp * 800 + fc16 * 8);
        *(bf16x8*)&s_w[0][swrow][swc * 8] = w0;
        *(bf16x8*)&s_f[0][frp][fc16 * 8]  = f0;
    }
    __syncthreads();

    // ---- bxc: [x(15), cx, cy, 0...] as B-fragments (k = 8g+j) ------------
    B8 bxc[2];
    #pragma unroll
    for (int f = 0; f < 2; ++f) {
        bxc[f].w[0] = bxc[f].w[1] = bxc[f].w[2] = bxc[f].w[3] = 0u;
        const float* xs = &s_x[wid][p + 16 * f][0];
        const int pp = pw + p + 16 * f;
        const float cx = -1.f + 2.f * (float)(pp >> 6) / 63.f;
        const float cy = -1.f + 2.f * (float)(pp & 63) / 63.f;
        if (g == 0) {
            bxc[f].w[0] = pk(xs[0], xs[1]);  bxc[f].w[1] = pk(xs[2], xs[3]);
            bxc[f].w[2] = pk(xs[4], xs[5]);  bxc[f].w[3] = pk(xs[6], xs[7]);
        } else if (g == 1) {
            bxc[f].w[0] = pk(xs[8], xs[9]);  bxc[f].w[1] = pk(xs[10], xs[11]);
            bxc[f].w[2] = pk(xs[12], xs[13]); bxc[f].w[3] = pk(xs[14], cx);
        } else if (g == 2) {
            bxc[f].w[0] = pk(cy, 0.f);
        }
    }

    // ---- A2: sh via MFMA -------------------------------------------------
    B8 bsh[4][2];
    #pragma unroll
    for (int ct = 0; ct < 8; ++ct) {
        const bf16x8 a_s = *(const bf16x8*)(sw1p + (16 * ct + p) * 32 + 8 * g);
        const int cb = 32 * (ct >> 1) + 8 * g + 4 * (ct & 1);
        const f32x4 b1 = *(const f32x4*)(sb1 + cb);
        const int m = ct >> 1, o = (ct & 1) * 2;
        #pragma unroll
        for (int f = 0; f < 2; ++f) {
            f32x4 cs = (f32x4){0.f, 0.f, 0.f, 0.f};
            cs = MFMA(a_s, bxc[f].v, cs);
            const float s0 = fmaxf(cs[0] + b1[0], 0.f), s1 = fmaxf(cs[1] + b1[1], 0.f);
            const float s2 = fmaxf(cs[2] + b1[2], 0.f), s3 = fmaxf(cs[3] + b1[3], 0.f);
            bsh[m][f].w[o] = pk(s0, s1); bsh[m][f].w[o + 1] = pk(s2, s3);
        }
    }

    // ---- B: kt loop, double-buffered LDS ---------------------------------
    f32x4 pv[8][2];
    #pragma unroll
    for (int ct = 0; ct < 8; ++ct)
        #pragma unroll
        for (int f = 0; f < 2; ++f) pv[ct][f] = (f32x4){0.f, 0.f, 0.f, 0.f};
    float psum0 = 0.f, psum1 = 0.f;

    for (int kt = 0; kt < 25; ++kt) {
        const int cur = kt & 1, nxt = cur ^ 1;
        // -- T14: issue next chunk's global loads first --
        bf16x8 stw0, stf0;
        if (kt < 24) {
            const int q0 = 32 * (kt + 1);
            stw0 = *(const bf16x8*)(sw2p + (size_t)(q0 + swrow) * C_ + swc * 8);
            stf0 = *(const bf16x8*)(filtn + (size_t)frp * 800 + q0 + fc16 * 8);
        }

        // -- compute current chunk from LDS --
        B8 bq[2];
        #pragma unroll
        for (int h = 0; h < 2; ++h) {
            const u16* wr = &s_w[cur][16 * h + p][8 * g];
            const bf16x8 aw0 = *(const bf16x8*)(wr);
            const bf16x8 aw1 = *(const bf16x8*)(wr + 32);
            const bf16x8 aw2 = *(const bf16x8*)(wr + 64);
            const bf16x8 aw3 = *(const bf16x8*)(wr + 96);
            const f32x4 bi = *(const f32x4*)(sb2p + 32 * kt + 8 * g + 4 * h);
            #pragma unroll
            for (int f = 0; f < 2; ++f) {
                f32x4 c4 = (f32x4){0.f, 0.f, 0.f, 0.f};
                c4 = MFMA(aw0, bsh[0][f].v, c4);
                c4 = MFMA(aw1, bsh[1][f].v, c4);
                c4 = MFMA(aw2, bsh[2][f].v, c4);
                c4 = MFMA(aw3, bsh[3][f].v, c4);
                const float e0 = __expf(fminf(c4[0] + bi[0], 60.f));
                const float e1 = __expf(fminf(c4[1] + bi[1], 60.f));
                const float e2 = __expf(fminf(c4[2] + bi[2], 60.f));
                const float e3 = __expf(fminf(c4[3] + bi[3], 60.f));
                if (f == 0) psum0 += (e0 + e1) + (e2 + e3);
                else        psum1 += (e0 + e1) + (e2 + e3);
                bq[f].w[2 * h + 0] = pk(e0, e1);
                bq[f].w[2 * h + 1] = pk(e2, e3);
            }
        }
        #pragma unroll
        for (int ct = 0; ct < 8; ++ct) {
            const bf16x8 af = *(const bf16x8*)&s_f[cur][16 * ct + p][8 * g];
            pv[ct][0] = MFMA(af, bq[0].v, pv[ct][0]);
            pv[ct][1] = MFMA(af, bq[1].v, pv[ct][1]);
        }

        // -- write staged data into the other buffer --
        if (kt < 24) {
            *(bf16x8*)&s_w[nxt][swrow][swc * 8] = stw0;
            *(bf16x8*)&s_f[nxt][frp][fc16 * 8]  = stf0;
        }
        __syncthreads();
    }
    psum0 += __shfl_xor(psum0, 16); psum0 += __shfl_xor(psum0, 32);
    psum1 += __shfl_xor(psum1, 16); psum1 += __shfl_xor(psum1, 32);
    const float inv0 = 1.f / psum0, inv1 = 1.f / psum1;

    // ---- C-pre: gh via MFMA (from bxc; k>=15 weight rows zero) -----------
    B8 bgh[4][2];
    #pragma unroll
    for (int ct = 0; ct < 8; ++ct) {
        const bf16x8 a_g = *(const bf16x8*)(gw1p + (16 * ct + p) * 32 + 8 * g);
        const int cb = 32 * (ct >> 1) + 8 * g + 4 * (ct & 1);
        const f32x4 b2 = *(const f32x4*)(gb1 + cb);
        const f32x4 gg = *(const f32x4*)(glob_gh + n * C_ + cb);
        const int m = ct >> 1, o = (ct & 1) * 2;
        #pragma unroll
        for (int f = 0; f < 2; ++f) {
            f32x4 cg = (f32x4){0.f, 0.f, 0.f, 0.f};
            cg = MFMA(a_g, bxc[f].v, cg);
            const float g0 = fmaxf(cg[0] + b2[0] + gg[0], 0.f), g1 = fmaxf(cg[1] + b2[1] + gg[1], 0.f);
            const float g2 = fmaxf(cg[2] + b2[2] + gg[2], 0.f), g3 = fmaxf(cg[3] + b2[3] + gg[3], 0.f);
            bgh[m][f].w[o] = pk(g0, g1); bgh[m][f].w[o + 1] = pk(g2, g3);
        }
    }

    // ---- C: gattn = sigmoid(gw2.gh + gb2); sf = gattn * pv * inv ---------
    B8 bsf[4][2];
    #pragma unroll
    for (int ct = 0; ct < 8; ++ct) {
        const u16* ar = gw2p + (16 * ct + p) * C_ + 8 * g;
        const bf16x8 a0 = *(const bf16x8*)(ar),      a1 = *(const bf16x8*)(ar + 32);
        const bf16x8 a2 = *(const bf16x8*)(ar + 64), a3 = *(const bf16x8*)(ar + 96);
        const int cb = 32 * (ct >> 1) + 8 * g + 4 * (ct & 1);
        const f32x4 gb = *(const f32x4*)(gb2 + cb);
        const int m = ct >> 1, o = (ct & 1) * 2;
        #pragma unroll
        for (int f = 0; f < 2; ++f) {
            f32x4 acc = (f32x4){0.f, 0.f, 0.f, 0.f};
            acc = MFMA(a0, bgh[0][f].v, acc);
            acc = MFMA(a1, bgh[1][f].v, acc);
            acc = MFMA(a2, bgh[2][f].v, acc);
            acc = MFMA(a3, bgh[3][f].v, acc);
            const float iv = f ? inv1 : inv0;
            const float s0 = pv[ct][f][0] * iv / (1.f + __expf(-(acc[0] + gb[0])));
            const float s1 = pv[ct][f][1] * iv / (1.f + __expf(-(acc[1] + gb[1])));
            const float s2 = pv[ct][f][2] * iv / (1.f + __expf(-(acc[2] + gb[2])));
            const float s3 = pv[ct][f][3] * iv / (1.f + __expf(-(acc[3] + gb[3])));
            bsf[m][f].w[o] = pk(s0, s1); bsf[m][f].w[o + 1] = pk(s2, s3);
        }
    }

    // ---- D: h1 = relu(fw1b.sf + fw1s.[x,cx,cy] + glob + fb1) -------------
    B8 bh1[4][2];
    #pragma unroll
    for (int ct = 0; ct < 8; ++ct) {
        const u16* ar = fw1bp + (16 * ct + p) * C_ + 8 * g;
        const bf16x8 a0 = *(const bf16x8*)(ar),      a1 = *(const bf16x8*)(ar + 32);
        const bf16x8 a2 = *(const bf16x8*)(ar + 64), a3 = *(const bf16x8*)(ar + 96);
        const bf16x8 a_s = *(const bf16x8*)(fw1sp + (16 * ct + p) * 32 + 8 * g);
        const int cb = 32 * (ct >> 1) + 8 * g + 4 * (ct & 1);
        const f32x4 fbv = *(const f32x4*)(fb1 + cb);
        const f32x4 gf  = *(const f32x4*)(glob_f1 + n * C_ + cb);
        const int m = ct >> 1, o = (ct & 1) * 2;
        #pragma unroll
        for (int f = 0; f < 2; ++f) {
            f32x4 acc = (f32x4){0.f, 0.f, 0.f, 0.f};
            acc = MFMA(a0, bsf[0][f].v, acc);
            acc = MFMA(a1, bsf[1][f].v, acc);
            acc = MFMA(a2, bsf[2][f].v, acc);
            acc = MFMA(a3, bsf[3][f].v, acc);
            acc = MFMA(a_s, bxc[f].v, acc);      // x/coord side-term
            const float h0 = fmaxf(acc[0] + fbv[0] + gf[0], 0.f);
            const float h1v = fmaxf(acc[1] + fbv[1] + gf[1], 0.f);
            const float h2 = fmaxf(acc[2] + fbv[2] + gf[2], 0.f);
            const float h3 = fmaxf(acc[3] + fbv[3] + gf[3], 0.f);
            bh1[m][f].w[o] = pk(h0, h1v); bh1[m][f].w[o + 1] = pk(h2, h3);
        }
    }

    // ---- E+F fused: h2 = relu(fw2.h1 + fb2); d += h2 * fw3 ---------------
    float d0[2] = {0.f, 0.f}, d1[2] = {0.f, 0.f}, d2[2] = {0.f, 0.f};
    #pragma unroll
    for (int ct = 0; ct < 8; ++ct) {
        const u16* ar = fw2p + (16 * ct + p) * C_ + 8 * g;
        const bf16x8 a0 = *(const bf16x8*)(ar),      a1 = *(const bf16x8*)(ar + 32);
        const bf16x8 a2 = *(const bf16x8*)(ar + 64), a3 = *(const bf16x8*)(ar + 96);
        const int cb = 32 * (ct >> 1) + 8 * g + 4 * (ct & 1);
        const f32x4 o4 = *(const f32x4*)(fb2 + cb);
        f32x4 w3r[4];
        #pragma unroll
        for (int r = 0; r < 4; ++r)
            w3r[r] = *(const f32x4*)(fw3p + (16 * ct + 4 * g + r) * 4);
        #pragma unroll
        for (int f = 0; f < 2; ++f) {
            f32x4 acc = (f32x4){0.f, 0.f, 0.f, 0.f};
            acc = MFMA(a0, bh1[0][f].v, acc);
            acc = MFMA(a1, bh1[1][f].v, acc);
            acc = MFMA(a2, bh1[2][f].v, acc);
            acc = MFMA(a3, bh1[3][f].v, acc);
            #pragma unroll
            for (int r = 0; r < 4; ++r) {
                const float h = fmaxf(acc[r] + o4[r], 0.f);
                d0[f] += h * w3r[r][0];
                d1[f] += h * w3r[r][1];
                d2[f] += h * w3r[r][2];
            }
        }
    }
    #pragma unroll
    for (int f = 0; f < 2; ++f) {
        float a0 = d0[f], a1 = d1[f], a2 = d2[f];
        a0 += __shfl_xor(a0, 16); a0 += __shfl_xor(a0, 32);
        a1 += __shfl_xor(a1, 16); a1 += __shfl_xor(a1, 32);
        a2 += __shfl_xor(a2, 16); a2 += __shfl_xor(a2, 32);
        if (g == 0) {
            const int pt = p + 16 * f;
            const int gp = n * P_ + pw + pt;
            out[gp * 3 + 0] = a0 + fb3[0] + s_x[wid][pt][0];
            out[gp * 3 + 1] = a1 + fb3[1] + s_x[wid][pt][1];
            out[gp * 3 + 2] = a2 + fb3[2] + s_x[wid][pt][2];
        }
    }
}

// ---------------------------------------------------------------------------
// Per-batch normalize in place (f32), 1024 threads.
// ---------------------------------------------------------------------------
__global__ __launch_bounds__(1024) void k_norm(float* __restrict__ out)
{
    __shared__ float red[48];
    __shared__ float red2[16];
    const int n = blockIdx.x, tid = threadIdx.x;
    float* pb = out + (size_t)n * P_ * 3;

    float sx = 0.f, sy = 0.f, sz = 0.f;
    for (int i = tid; i < P_; i += 1024) {
        sx += pb[i * 3 + 0]; sy += pb[i * 3 + 1]; sz += pb[i * 3 + 2];
    }
    #pragma unroll
    for (int m = 32; m >= 1; m >>= 1) {
        sx += __shfl_xor(sx, m); sy += __shfl_xor(sy, m); sz += __shfl_xor(sz, m);
    }
    const int wv = tid >> 6, ln = tid & 63;
    if (ln == 0) { red[wv * 3 + 0] = sx; red[wv * 3 + 1] = sy; red[wv * 3 + 2] = sz; }
    __syncthreads();
    float meanx = 0.f, meany = 0.f, meanz = 0.f;
    #pragma unroll
    for (int w = 0; w < 16; ++w) {
        meanx += red[w * 3 + 0]; meany += red[w * 3 + 1]; meanz += red[w * 3 + 2];
    }
    meanx /= (float)P_; meany /= (float)P_; meanz /= (float)P_;

    float mm = 0.f;
    for (int i = tid; i < P_; i += 1024) {
        const float dx = pb[i * 3 + 0] - meanx;
        const float dy = pb[i * 3 + 1] - meany;
        const float dz = pb[i * 3 + 2] - meanz;
        mm = fmaxf(mm, dx * dx + dy * dy + dz * dz);
    }
    #pragma unroll
    for (int m = 32; m >= 1; m >>= 1) mm = fmaxf(mm, __shfl_xor(mm, m));
    if (ln == 0) red2[wv] = mm;
    __syncthreads();
    mm = 0.f;
    #pragma unroll
    for (int w = 0; w < 16; ++w) mm = fmaxf(mm, red2[w]);
    const float scale = 1.f / (sqrtf(mm) + 1e-8f);

    for (int i = tid; i < P_; i += 1024) {
        pb[i * 3 + 0] = (pb[i * 3 + 0] - meanx) * scale;
        pb[i * 3 + 1] = (pb[i * 3 + 1] - meany) * scale;
        pb[i * 3 + 2] = (pb[i * 3 + 2] - meanz) * scale;
    }
}

// ---------------------------------------------------------------------------
extern "C" void kernel_launch(void* const* d_in, const int* in_sizes, int n_in,
                              void* d_out, int out_size, void* d_ws, size_t ws_size,
                              hipStream_t stream) {
    const float* points    = (const float*)d_in[0];
    const float* transform = (const float*)d_in[1];
    const float* filters   = (const float*)d_in[2];
    const float* enc_glob  = (const float*)d_in[3];
    const float* sw1 = (const float*)d_in[4];
    const float* sb1 = (const float*)d_in[5];
    const float* sw2 = (const float*)d_in[6];
    const float* sb2 = (const float*)d_in[7];
    const float* gw1 = (const float*)d_in[8];
    const float* gb1 = (const float*)d_in[9];
    const float* gw2 = (const float*)d_in[10];
    const float* gb2 = (const float*)d_in[11];
    const float* fw1 = (const float*)d_in[12];
    const float* fb1 = (const float*)d_in[13];
    const float* fw2 = (const float*)d_in[14];
    const float* fb2 = (const float*)d_in[15];
    const float* fw3 = (const float*)d_in[16];
    const float* fb3 = (const float*)d_in[17];

    char* ws = (char*)d_ws;
    u16*   sw2p    = (u16*)(ws + OFF_SW2P);
    u16*   sw1p    = (u16*)(ws + OFF_SW1P);
    u16*   gw1p    = (u16*)(ws + OFF_GW1P);
    u16*   gw2p    = (u16*)(ws + OFF_GW2P);
    u16*   fw1bp   = (u16*)(ws + OFF_FW1BP);
    u16*   fw2p    = (u16*)(ws + OFF_FW2P);
    float* sb2p    = (float*)(ws + OFF_SB2P);
    float* glob_gh = (float*)(ws + OFF_GLOBGH);
    float* glob_f1 = (float*)(ws + OFF_GLOBF1);
    u16*   fw1sp   = (u16*)(ws + OFF_FW1SP);
    float* fw3p    = (float*)(ws + OFF_FW3P);
    u16*   filtp   = (u16*)(ws + OFF_FILTP);
    float* out     = (float*)d_out;

    k_prep<<<(E10 + 255) / 256, 256, 0, stream>>>(
        sw1, sw2, sb2, gw1, gw2, fw1, fw2, fw3, filters, enc_glob,
        sw2p, sw1p, gw1p, gw2p, fw1bp, fw2p, sb2p, fw1sp, fw3p, filtp,
        glob_gh, glob_f1);
    k_mfma<<<N_ * (P_ / 256), 512, 0, stream>>>(
        points, transform, sb1, gb1, gb2, fb1, fb2, fb3,
        sw1p, gw1p, sw2p, sb2p, gw2p, fw1bp, fw2p, fw1sp, fw3p, filtp,
        glob_gh, glob_f1, out);
    k_norm<<<N_, 1024, 0, stream>>>(out);
}

// Round 14
// 171.338 us; speedup vs baseline: 1.1864x; 1.0637x over previous
//
#include <hip/hip_runtime.h>
#include <hip/hip_bf16.h>

#define N_   16
#define P_   4096
#define C_   128
#define HW_  784
#define G_   512

typedef unsigned short u16;
typedef unsigned int   u32;
typedef __attribute__((ext_vector_type(8))) short bf16x8;
typedef __attribute__((ext_vector_type(4))) float f32x4;

union B8 { bf16x8 v; u32 w[4]; };

#define MFMA(a,b,c) __builtin_amdgcn_mfma_f32_16x16x32_bf16((a),(b),(c),0,0,0)

__device__ __forceinline__ u16 f2b(float f) {
    __hip_bfloat16 h = __float2bfloat16(f);
    return *reinterpret_cast<u16*>(&h);
}
__device__ __forceinline__ u32 pk(float lo, float hi) {
    return (u32)f2b(lo) | ((u32)f2b(hi) << 16);
}

// ---------------------------------------------------------------------------
// ws layout (bytes). bf16 A-operand matrices stored with M-dim rows PERMUTED
// so MFMA D-layout (row=4g+reg) lands in B-fragment k-order (k=8g+j):
//   row position (16ct + r) holds true idx 32*(ct>>1) + 8*(r>>2) + 4*(ct&1) + (r&3)
// ---------------------------------------------------------------------------
#define OFF_SW2P    0         // 800x128 bf16 (q rows permuted, q>=784 zero)
#define OFF_SW1P    204800    // 128x32 bf16 (out-c permuted, k>=15 zero)
#define OFF_GW1P    212992    // 128x32 bf16
#define OFF_GW2P    221184    // 128x128 bf16 (out-c permuted)
#define OFF_FW1BP   253952    // 128x128 bf16 (out-c permuted, fw1 rows 529+)
#define OFF_FW2P    286720    // 128x128 bf16 (out-c permuted)
#define OFF_SB2P    319488    // 800 f32 (plain order, q>=784 = -1e30)
#define OFF_GLOBGH  322688    // 16x128 f32
#define OFF_GLOBF1  330880    // 16x128 f32
#define OFF_FW1SP   339072    // 128x32 bf16 (perm rows; k<15 fw1[k], 15->527, 16->528, else 0)
#define OFF_FW3P    347264    // 128x4 f32 (perm rows of fw3, 4th = 0)
#define OFF_FILTP   349312    // 16x128x800 bf16 (c rows permuted, q>=784 zero)

// prep segment ends (flat thread index)
#define E0 102400   // sw2p  800*128
#define E1 110592   // sw1p  128*32
#define E2 118784   // gw1p  128*32
#define E3 135168   // gw2p  128*128
#define E4 151552   // fw1bp 128*128
#define E5 167936   // fw2p  128*128
#define E6 168736   // sb2p  800
#define E7 185120   // glob  2*16*128*4 (4-way k-split)
#define E8 189216   // fw1sp 128*32
#define E9 189728   // fw3p  128*4
#define E10 599328  // filtp 16*128*200 (4 elems per thread, 784%4==0)

__device__ __forceinline__ int perm_c(int row) {   // row pos -> true index
    const int ct = row >> 4, r = row & 15;
    return 32 * (ct >> 1) + 8 * (r >> 2) + 4 * (ct & 1) + (r & 3);
}

// ---------------------------------------------------------------------------
__global__ __launch_bounds__(256) void k_prep(
    const float* __restrict__ sw1, const float* __restrict__ sw2,
    const float* __restrict__ sb2, const float* __restrict__ gw1,
    const float* __restrict__ gw2, const float* __restrict__ fw1,
    const float* __restrict__ fw2, const float* __restrict__ fw3,
    const float* __restrict__ filters, const float* __restrict__ enc_glob,
    u16* __restrict__ sw2p, u16* __restrict__ sw1p, u16* __restrict__ gw1p,
    u16* __restrict__ gw2p, u16* __restrict__ fw1bp, u16* __restrict__ fw2p,
    float* __restrict__ sb2p, u16* __restrict__ fw1sp, float* __restrict__ fw3p,
    u16* __restrict__ filtp,
    float* __restrict__ glob_gh, float* __restrict__ glob_f1)
{
    const int idx = blockIdx.x * 256 + threadIdx.x;
    if (idx < E0) {                       // sw2p: q-rows permuted per 32-block
        const int r_new = idx >> 7, c = idx & 127;
        const int kt = r_new >> 5, o = r_new & 31, h = (o >> 4) & 1, r = o & 15;
        const int q = kt * 32 + 8 * (r >> 2) + 4 * h + (r & 3);
        sw2p[idx] = (q < HW_) ? f2b(sw2[c * HW_ + q]) : (u16)0;
    } else if (idx < E1) {                // sw1p
        const int t = idx - E0;
        const int row = t >> 5, k = t & 31;
        const int c = perm_c(row);
        sw1p[t] = (k < 15) ? f2b(sw1[k * C_ + c]) : (u16)0;
    } else if (idx < E2) {                // gw1p
        const int t = idx - E1;
        const int row = t >> 5, k = t & 31;
        const int c = perm_c(row);
        gw1p[t] = (k < 15) ? f2b(gw1[k * C_ + c]) : (u16)0;
    } else if (idx < E3) {                // gw2p
        const int t = idx - E2;
        const int row = t >> 7, ci = t & 127;
        gw2p[t] = f2b(gw2[ci * C_ + perm_c(row)]);
    } else if (idx < E4) {                // fw1bp (fw1 rows 529..656)
        const int t = idx - E3;
        const int row = t >> 7, ci = t & 127;
        fw1bp[t] = f2b(fw1[(529 + ci) * C_ + perm_c(row)]);
    } else if (idx < E5) {                // fw2p
        const int t = idx - E4;
        const int row = t >> 7, ci = t & 127;
        fw2p[t] = f2b(fw2[ci * C_ + perm_c(row)]);
    } else if (idx < E6) {                // sb2p: plain order + -inf tail
        const int q = idx - E5;
        sb2p[q] = (q < HW_) ? sb2[q] : -1e30f;
    } else if (idx < E7) {                // glob: 4 threads per output, k-split
        const int t = idx - E6;           // 0..16383
        const int sub = t & 3, r = t >> 2;
        const int which = r >> 11, nn = (r >> 7) & 15, c = r & 127;
        const float* W = which ? fw1 : gw1;
        const float* gv = enc_glob + nn * G_ + sub * 128;
        const float* Wp = W + (15 + sub * 128) * C_ + c;
        float acc = 0.f;
        for (int k = 0; k < 128; ++k) acc += gv[k] * Wp[k * C_];
        acc += __shfl_xor(acc, 1);
        acc += __shfl_xor(acc, 2);
        if (sub == 0) (which ? glob_f1 : glob_gh)[nn * C_ + c] = acc;
    } else if (idx < E8) {                // fw1sp: x/coord side-weights
        const int t = idx - E7;
        const int row = t >> 5, k = t & 31;
        const int c = perm_c(row);
        float v = 0.f;
        if (k < 15)       v = fw1[k * C_ + c];
        else if (k == 15) v = fw1[527 * C_ + c];
        else if (k == 16) v = fw1[528 * C_ + c];
        fw1sp[t] = f2b(v);
    } else if (idx < E9) {                // fw3p: perm rows of fw3, padded
        const int t = idx - E8;
        const int row = t >> 2, j = t & 3;
        fw3p[t] = (j < 3) ? fw3[perm_c(row) * 3 + j] : 0.f;
    } else if (idx < E10) {               // filtp: 4 elems/thread (784%4==0)
        const int t = idx - E9;
        const int nn = t / 25600;
        const int rr = t % 25600;
        const int row = rr / 200, qg = rr % 200;
        const int q0 = qg * 4;
        const int c = perm_c(row);
        u32 lo = 0u, hi = 0u;
        if (q0 < HW_) {                   // full in-bounds vec4 (q0 <= 780)
            const f32x4 v = *(const f32x4*)(filters + ((size_t)nn * C_ + c) * HW_ + q0);
            lo = pk(v[0], v[1]); hi = pk(v[2], v[3]);
        }
        const size_t base = (size_t)nn * 102400 + (size_t)row * 800 + q0;
        *(uint2*)(filtp + base) = make_uint2(lo, hi);
    }
}

// ---------------------------------------------------------------------------
// Main kernel: 256 points/block, 8 waves (512 threads), 32 points/wave.
// Round-14 change: 2-chunk-ahead register prefetch (T4 counted-wait via reg
// deps) -- the ds_write at the bottom of step k consumes registers whose
// global loads were issued a FULL iteration earlier (~7k cy in flight), so
// L2/L3 latency is off the per-iteration critical path. Hand-unrolled x2
// body keeps staging regs statically named (rule #20). sb2p biases moved to
// LDS (s_b, broadcast reads) -- removes an L2 load from the exp critical
// path. Tripwires: WRITE_SIZE ~768 KB, VGPR <= ~140.
// ---------------------------------------------------------------------------
__global__ __launch_bounds__(512, 2) void k_mfma(
    const float* __restrict__ points, const float* __restrict__ transform,
    const float* __restrict__ sb1, const float* __restrict__ gb1,
    const float* __restrict__ gb2, const float* __restrict__ fb1,
    const float* __restrict__ fb2, const float* __restrict__ fb3,
    const u16* __restrict__ sw1p, const u16* __restrict__ gw1p,
    const u16* __restrict__ sw2p, const float* __restrict__ sb2p,
    const u16* __restrict__ gw2p, const u16* __restrict__ fw1bp,
    const u16* __restrict__ fw2p, const u16* __restrict__ fw1sp,
    const float* __restrict__ fw3p, const u16* __restrict__ filtp,
    const float* __restrict__ glob_gh, const float* __restrict__ glob_f1,
    float* __restrict__ out)
{
    __shared__ __align__(16) float s_x[8][32][16];   // 16 KB
    __shared__ __align__(16) u16 s_w[2][32][136];    // 17408 B
    __shared__ __align__(16) u16 s_f[2][128][36];    // 18432 B
    __shared__ __align__(16) float s_b[800];         // 3200 B  (total 55.0 KB)

    const int tid = threadIdx.x, wid = tid >> 6, lane = tid & 63;
    const int p = lane & 15, g = lane >> 4;
    // XCD swizzle: 256 blocks, 32-chunk per XCD -> 2 distinct n per XCD L2.
    const int bid = blockIdx.x;
    const int nb  = (bid & 7) * 32 + (bid >> 3);
    const int n   = nb >> 4;
    const int pw  = ((nb & 15) << 8) + (wid << 5);

    const u16* filtn = filtp + (size_t)n * 102400;
    // staging slot coords (fixed per thread; 512 threads -> ONE b128 each)
    const int swrow = tid >> 4, swc = tid & 15;   // sw2p row 0..31, 16B col
    const int frp   = tid >> 2, fc16 = tid & 3;   // filt row 0..127, 16B col

    // ---- A1: inputs to LDS (per-wave, 32 points) -------------------------
    for (int i = lane; i < 512; i += 64) {
        const int pt = i >> 4, k = i & 15;
        const int gp = n * P_ + pw + pt;
        float v = 0.f;
        if (k < 3)       v = points[gp * 3 + k];
        else if (k < 15) v = transform[gp * 12 + k - 3];
        s_x[wid][pt][k] = v;
    }

    // ---- stage chunk 0 into buffer 0; sb2p -> s_b; chunk 1 -> regs A -----
    {
        const bf16x8 w0 = *(const bf16x8*)(sw2p + (size_t)swrow * C_ + swc * 8);
        const bf16x8 f0 = *(const bf16x8*)(filtn + (size_t)frp * 800 + fc16 * 8);
        *(bf16x8*)&s_w[0][swrow][swc * 8] = w0;
        *(bf16x8*)&s_f[0][frp][fc16 * 8]  = f0;
        if (tid < 200)
            *(f32x4*)&s_b[tid * 4] = *(const f32x4*)(sb2p + tid * 4);
    }
    bf16x8 Aw = *(const bf16x8*)(sw2p + (size_t)(32 + swrow) * C_ + swc * 8);
    bf16x8 Af = *(const bf16x8*)(filtn + (size_t)frp * 800 + 32 + fc16 * 8);
    __syncthreads();

    // ---- bxc: [x(15), cx, cy, 0...] as B-fragments (k = 8g+j) ------------
    B8 bxc[2];
    #pragma unroll
    for (int f = 0; f < 2; ++f) {
        bxc[f].w[0] = bxc[f].w[1] = bxc[f].w[2] = bxc[f].w[3] = 0u;
        const float* xs = &s_x[wid][p + 16 * f][0];
        const int pp = pw + p + 16 * f;
        const float cx = -1.f + 2.f * (float)(pp >> 6) / 63.f;
        const float cy = -1.f + 2.f * (float)(pp & 63) / 63.f;
        if (g == 0) {
            bxc[f].w[0] = pk(xs[0], xs[1]);  bxc[f].w[1] = pk(xs[2], xs[3]);
            bxc[f].w[2] = pk(xs[4], xs[5]);  bxc[f].w[3] = pk(xs[6], xs[7]);
        } else if (g == 1) {
            bxc[f].w[0] = pk(xs[8], xs[9]);  bxc[f].w[1] = pk(xs[10], xs[11]);
            bxc[f].w[2] = pk(xs[12], xs[13]); bxc[f].w[3] = pk(xs[14], cx);
        } else if (g == 2) {
            bxc[f].w[0] = pk(cy, 0.f);
        }
    }

    // ---- A2: sh via MFMA -------------------------------------------------
    B8 bsh[4][2];
    #pragma unroll
    for (int ct = 0; ct < 8; ++ct) {
        const bf16x8 a_s = *(const bf16x8*)(sw1p + (16 * ct + p) * 32 + 8 * g);
        const int cb = 32 * (ct >> 1) + 8 * g + 4 * (ct & 1);
        const f32x4 b1 = *(const f32x4*)(sb1 + cb);
        const int m = ct >> 1, o = (ct & 1) * 2;
        #pragma unroll
        for (int f = 0; f < 2; ++f) {
            f32x4 cs = (f32x4){0.f, 0.f, 0.f, 0.f};
            cs = MFMA(a_s, bxc[f].v, cs);
            const float s0 = fmaxf(cs[0] + b1[0], 0.f), s1 = fmaxf(cs[1] + b1[1], 0.f);
            const float s2 = fmaxf(cs[2] + b1[2], 0.f), s3 = fmaxf(cs[3] + b1[3], 0.f);
            bsh[m][f].w[o] = pk(s0, s1); bsh[m][f].w[o + 1] = pk(s2, s3);
        }
    }

    // ---- B: kt loop, double-buffered LDS, 2-chunk-ahead prefetch ---------
    f32x4 pv[8][2];
    #pragma unroll
    for (int ct = 0; ct < 8; ++ct)
        #pragma unroll
        for (int f = 0; f < 2; ++f) pv[ct][f] = (f32x4){0.f, 0.f, 0.f, 0.f};
    float psum0 = 0.f, psum1 = 0.f;

#define COMPUTE_CHUNK(KT, BUF)                                                 \
    do {                                                                       \
        B8 bq[2];                                                              \
        _Pragma("unroll")                                                      \
        for (int h = 0; h < 2; ++h) {                                          \
            const u16* wr = &s_w[BUF][16 * h + p][8 * g];                      \
            const bf16x8 aw0 = *(const bf16x8*)(wr);                           \
            const bf16x8 aw1 = *(const bf16x8*)(wr + 32);                      \
            const bf16x8 aw2 = *(const bf16x8*)(wr + 64);                      \
            const bf16x8 aw3 = *(const bf16x8*)(wr + 96);                      \
            const f32x4 bi = *(const f32x4*)&s_b[32 * (KT) + 8 * g + 4 * h];   \
            _Pragma("unroll")                                                  \
            for (int f = 0; f < 2; ++f) {                                      \
                f32x4 c4 = (f32x4){0.f, 0.f, 0.f, 0.f};                        \
                c4 = MFMA(aw0, bsh[0][f].v, c4);                               \
                c4 = MFMA(aw1, bsh[1][f].v, c4);                               \
                c4 = MFMA(aw2, bsh[2][f].v, c4);                               \
                c4 = MFMA(aw3, bsh[3][f].v, c4);                               \
                const float e0 = __expf(fminf(c4[0] + bi[0], 60.f));           \
                const float e1 = __expf(fminf(c4[1] + bi[1], 60.f));           \
                const float e2 = __expf(fminf(c4[2] + bi[2], 60.f));           \
                const float e3 = __expf(fminf(c4[3] + bi[3], 60.f));           \
                if (f == 0) psum0 += (e0 + e1) + (e2 + e3);                    \
                else        psum1 += (e0 + e1) + (e2 + e3);                    \
                bq[f].w[2 * h + 0] = pk(e0, e1);                               \
                bq[f].w[2 * h + 1] = pk(e2, e3);                               \
            }                                                                  \
        }                                                                      \
        _Pragma("unroll")                                                      \
        for (int ct = 0; ct < 8; ++ct) {                                       \
            const bf16x8 af = *(const bf16x8*)&s_f[BUF][16 * ct + p][8 * g];   \
            pv[ct][0] = MFMA(af, bq[0].v, pv[ct][0]);                          \
            pv[ct][1] = MFMA(af, bq[1].v, pv[ct][1]);                          \
        }                                                                      \
    } while (0)

    bf16x8 Bw, Bf;
    for (int kt = 0; kt < 24; kt += 2) {
        // ---- even step: issue kt+2 -> B; compute kt (buf0); write A->buf1
        {
            const int q0 = 32 * (kt + 2);   // kt+2 in [2,24]: always valid
            Bw = *(const bf16x8*)(sw2p + (size_t)(q0 + swrow) * C_ + swc * 8);
            Bf = *(const bf16x8*)(filtn + (size_t)frp * 800 + q0 + fc16 * 8);
        }
        COMPUTE_CHUNK(kt, 0);
        *(bf16x8*)&s_w[1][swrow][swc * 8] = Aw;
        *(bf16x8*)&s_f[1][frp][fc16 * 8]  = Af;
        __syncthreads();

        // ---- odd step: issue kt+3 -> A; compute kt+1 (buf1); write B->buf0
        if (kt + 3 <= 24) {
            const int q0 = 32 * (kt + 3);
            Aw = *(const bf16x8*)(sw2p + (size_t)(q0 + swrow) * C_ + swc * 8);
            Af = *(const bf16x8*)(filtn + (size_t)frp * 800 + q0 + fc16 * 8);
        }
        COMPUTE_CHUNK(kt + 1, 1);
        *(bf16x8*)&s_w[0][swrow][swc * 8] = Bw;
        *(bf16x8*)&s_f[0][frp][fc16 * 8]  = Bf;
        __syncthreads();
    }
    // ---- tail: chunk 24 (buf0), no staging -------------------------------
    COMPUTE_CHUNK(24, 0);
#undef COMPUTE_CHUNK

    psum0 += __shfl_xor(psum0, 16); psum0 += __shfl_xor(psum0, 32);
    psum1 += __shfl_xor(psum1, 16); psum1 += __shfl_xor(psum1, 32);
    const float inv0 = 1.f / psum0, inv1 = 1.f / psum1;

    // ---- C-pre: gh via MFMA (from bxc; k>=15 weight rows zero) -----------
    B8 bgh[4][2];
    #pragma unroll
    for (int ct = 0; ct < 8; ++ct) {
        const bf16x8 a_g = *(const bf16x8*)(gw1p + (16 * ct + p) * 32 + 8 * g);
        const int cb = 32 * (ct >> 1) + 8 * g + 4 * (ct & 1);
        const f32x4 b2 = *(const f32x4*)(gb1 + cb);
        const f32x4 gg = *(const f32x4*)(glob_gh + n * C_ + cb);
        const int m = ct >> 1, o = (ct & 1) * 2;
        #pragma unroll
        for (int f = 0; f < 2; ++f) {
            f32x4 cg = (f32x4){0.f, 0.f, 0.f, 0.f};
            cg = MFMA(a_g, bxc[f].v, cg);
            const float g0 = fmaxf(cg[0] + b2[0] + gg[0], 0.f), g1 = fmaxf(cg[1] + b2[1] + gg[1], 0.f);
            const float g2 = fmaxf(cg[2] + b2[2] + gg[2], 0.f), g3 = fmaxf(cg[3] + b2[3] + gg[3], 0.f);
            bgh[m][f].w[o] = pk(g0, g1); bgh[m][f].w[o + 1] = pk(g2, g3);
        }
    }

    // ---- C: gattn = sigmoid(gw2.gh + gb2); sf = gattn * pv * inv ---------
    B8 bsf[4][2];
    #pragma unroll
    for (int ct = 0; ct < 8; ++ct) {
        const u16* ar = gw2p + (16 * ct + p) * C_ + 8 * g;
        const bf16x8 a0 = *(const bf16x8*)(ar),      a1 = *(const bf16x8*)(ar + 32);
        const bf16x8 a2 = *(const bf16x8*)(ar + 64), a3 = *(const bf16x8*)(ar + 96);
        const int cb = 32 * (ct >> 1) + 8 * g + 4 * (ct & 1);
        const f32x4 gb = *(const f32x4*)(gb2 + cb);
        const int m = ct >> 1, o = (ct & 1) * 2;
        #pragma unroll
        for (int f = 0; f < 2; ++f) {
            f32x4 acc = (f32x4){0.f, 0.f, 0.f, 0.f};
            acc = MFMA(a0, bgh[0][f].v, acc);
            acc = MFMA(a1, bgh[1][f].v, acc);
            acc = MFMA(a2, bgh[2][f].v, acc);
            acc = MFMA(a3, bgh[3][f].v, acc);
            const float iv = f ? inv1 : inv0;
            const float s0 = pv[ct][f][0] * iv / (1.f + __expf(-(acc[0] + gb[0])));
            const float s1 = pv[ct][f][1] * iv / (1.f + __expf(-(acc[1] + gb[1])));
            const float s2 = pv[ct][f][2] * iv / (1.f + __expf(-(acc[2] + gb[2])));
            const float s3 = pv[ct][f][3] * iv / (1.f + __expf(-(acc[3] + gb[3])));
            bsf[m][f].w[o] = pk(s0, s1); bsf[m][f].w[o + 1] = pk(s2, s3);
        }
    }

    // ---- D: h1 = relu(fw1b.sf + fw1s.[x,cx,cy] + glob + fb1) -------------
    B8 bh1[4][2];
    #pragma unroll
    for (int ct = 0; ct < 8; ++ct) {
        const u16* ar = fw1bp + (16 * ct + p) * C_ + 8 * g;
        const bf16x8 a0 = *(const bf16x8*)(ar),      a1 = *(const bf16x8*)(ar + 32);
        const bf16x8 a2 = *(const bf16x8*)(ar + 64), a3 = *(const bf16x8*)(ar + 96);
        const bf16x8 a_s = *(const bf16x8*)(fw1sp + (16 * ct + p) * 32 + 8 * g);
        const int cb = 32 * (ct >> 1) + 8 * g + 4 * (ct & 1);
        const f32x4 fbv = *(const f32x4*)(fb1 + cb);
        const f32x4 gf  = *(const f32x4*)(glob_f1 + n * C_ + cb);
        const int m = ct >> 1, o = (ct & 1) * 2;
        #pragma unroll
        for (int f = 0; f < 2; ++f) {
            f32x4 acc = (f32x4){0.f, 0.f, 0.f, 0.f};
            acc = MFMA(a0, bsf[0][f].v, acc);
            acc = MFMA(a1, bsf[1][f].v, acc);
            acc = MFMA(a2, bsf[2][f].v, acc);
            acc = MFMA(a3, bsf[3][f].v, acc);
            acc = MFMA(a_s, bxc[f].v, acc);      // x/coord side-term
            const float h0 = fmaxf(acc[0] + fbv[0] + gf[0], 0.f);
            const float h1v = fmaxf(acc[1] + fbv[1] + gf[1], 0.f);
            const float h2 = fmaxf(acc[2] + fbv[2] + gf[2], 0.f);
            const float h3 = fmaxf(acc[3] + fbv[3] + gf[3], 0.f);
            bh1[m][f].w[o] = pk(h0, h1v); bh1[m][f].w[o + 1] = pk(h2, h3);
        }
    }

    // ---- E+F fused: h2 = relu(fw2.h1 + fb2); d += h2 * fw3 ---------------
    float d0[2] = {0.f, 0.f}, d1[2] = {0.f, 0.f}, d2[2] = {0.f, 0.f};
    #pragma unroll
    for (int ct = 0; ct < 8; ++ct) {
        const u16* ar = fw2p + (16 * ct + p) * C_ + 8 * g;
        const bf16x8 a0 = *(const bf16x8*)(ar),      a1 = *(const bf16x8*)(ar + 32);
        const bf16x8 a2 = *(const bf16x8*)(ar + 64), a3 = *(const bf16x8*)(ar + 96);
        const int cb = 32 * (ct >> 1) + 8 * g + 4 * (ct & 1);
        const f32x4 o4 = *(const f32x4*)(fb2 + cb);
        f32x4 w3r[4];
        #pragma unroll
        for (int r = 0; r < 4; ++r)
            w3r[r] = *(const f32x4*)(fw3p + (16 * ct + 4 * g + r) * 4);
        #pragma unroll
        for (int f = 0; f < 2; ++f) {
            f32x4 acc = (f32x4){0.f, 0.f, 0.f, 0.f};
            acc = MFMA(a0, bh1[0][f].v, acc);
            acc = MFMA(a1, bh1[1][f].v, acc);
            acc = MFMA(a2, bh1[2][f].v, acc);
            acc = MFMA(a3, bh1[3][f].v, acc);
            #pragma unroll
            for (int r = 0; r < 4; ++r) {
                const float h = fmaxf(acc[r] + o4[r], 0.f);
                d0[f] += h * w3r[r][0];
                d1[f] += h * w3r[r][1];
                d2[f] += h * w3r[r][2];
            }
        }
    }
    #pragma unroll
    for (int f = 0; f < 2; ++f) {
        float a0 = d0[f], a1 = d1[f], a2 = d2[f];
        a0 += __shfl_xor(a0, 16); a0 += __shfl_xor(a0, 32);
        a1 += __shfl_xor(a1, 16); a1 += __shfl_xor(a1, 32);
        a2 += __shfl_xor(a2, 16); a2 += __shfl_xor(a2, 32);
        if (g == 0) {
            const int pt = p + 16 * f;
            const int gp = n * P_ + pw + pt;
            out[gp * 3 + 0] = a0 + fb3[0] + s_x[wid][pt][0];
            out[gp * 3 + 1] = a1 + fb3[1] + s_x[wid][pt][1];
            out[gp * 3 + 2] = a2 + fb3[2] + s_x[wid][pt][2];
        }
    }
}

// ---------------------------------------------------------------------------
// Per-batch normalize in place (f32), 1024 threads.
// ---------------------------------------------------------------------------
__global__ __launch_bounds__(1024) void k_norm(float* __restrict__ out)
{
    __shared__ float red[48];
    __shared__ float red2[16];
    const int n = blockIdx.x, tid = threadIdx.x;
    float* pb = out + (size_t)n * P_ * 3;

    float sx = 0.f, sy = 0.f, sz = 0.f;
    for (int i = tid; i < P_; i += 1024) {
        sx += pb[i * 3 + 0]; sy += pb[i * 3 + 1]; sz += pb[i * 3 + 2];
    }
    #pragma unroll
    for (int m = 32; m >= 1; m >>= 1) {
        sx += __shfl_xor(sx, m); sy += __shfl_xor(sy, m); sz += __shfl_xor(sz, m);
    }
    const int wv = tid >> 6, ln = tid & 63;
    if (ln == 0) { red[wv * 3 + 0] = sx; red[wv * 3 + 1] = sy; red[wv * 3 + 2] = sz; }
    __syncthreads();
    float meanx = 0.f, meany = 0.f, meanz = 0.f;
    #pragma unroll
    for (int w = 0; w < 16; ++w) {
        meanx += red[w * 3 + 0]; meany += red[w * 3 + 1]; meanz += red[w * 3 + 2];
    }
    meanx /= (float)P_; meany /= (float)P_; meanz /= (float)P_;

    float mm = 0.f;
    for (int i = tid; i < P_; i += 1024) {
        const float dx = pb[i * 3 + 0] - meanx;
        const float dy = pb[i * 3 + 1] - meany;
        const float dz = pb[i * 3 + 2] - meanz;
        mm = fmaxf(mm, dx * dx + dy * dy + dz * dz);
    }
    #pragma unroll
    for (int m = 32; m >= 1; m >>= 1) mm = fmaxf(mm, __shfl_xor(mm, m));
    if (ln == 0) red2[wv] = mm;
    __syncthreads();
    mm = 0.f;
    #pragma unroll
    for (int w = 0; w < 16; ++w) mm = fmaxf(mm, red2[w]);
    const float scale = 1.f / (sqrtf(mm) + 1e-8f);

    for (int i = tid; i < P_; i += 1024) {
        pb[i * 3 + 0] = (pb[i * 3 + 0] - meanx) * scale;
        pb[i * 3 + 1] = (pb[i * 3 + 1] - meany) * scale;
        pb[i * 3 + 2] = (pb[i * 3 + 2] - meanz) * scale;
    }
}

// ---------------------------------------------------------------------------
extern "C" void kernel_launch(void* const* d_in, const int* in_sizes, int n_in,
                              void* d_out, int out_size, void* d_ws, size_t ws_size,
                              hipStream_t stream) {
    const float* points    = (const float*)d_in[0];
    const float* transform = (const float*)d_in[1];
    const float* filters   = (const float*)d_in[2];
    const float* enc_glob  = (const float*)d_in[3];
    const float* sw1 = (const float*)d_in[4];
    const float* sb1 = (const float*)d_in[5];
    const float* sw2 = (const float*)d_in[6];
    const float* sb2 = (const float*)d_in[7];
    const float* gw1 = (const float*)d_in[8];
    const float* gb1 = (const float*)d_in[9];
    const float* gw2 = (const float*)d_in[10];
    const float* gb2 = (const float*)d_in[11];
    const float* fw1 = (const float*)d_in[12];
    const float* fb1 = (const float*)d_in[13];
    const float* fw2 = (const float*)d_in[14];
    const float* fb2 = (const float*)d_in[15];
    const float* fw3 = (const float*)d_in[16];
    const float* fb3 = (const float*)d_in[17];

    char* ws = (char*)d_ws;
    u16*   sw2p    = (u16*)(ws + OFF_SW2P);
    u16*   sw1p    = (u16*)(ws + OFF_SW1P);
    u16*   gw1p    = (u16*)(ws + OFF_GW1P);
    u16*   gw2p    = (u16*)(ws + OFF_GW2P);
    u16*   fw1bp   = (u16*)(ws + OFF_FW1BP);
    u16*   fw2p    = (u16*)(ws + OFF_FW2P);
    float* sb2p    = (float*)(ws + OFF_SB2P);
    float* glob_gh = (float*)(ws + OFF_GLOBGH);
    float* glob_f1 = (float*)(ws + OFF_GLOBF1);
    u16*   fw1sp   = (u16*)(ws + OFF_FW1SP);
    float* fw3p    = (float*)(ws + OFF_FW3P);
    u16*   filtp   = (u16*)(ws + OFF_FILTP);
    float* out     = (float*)d_out;

    k_prep<<<(E10 + 255) / 256, 256, 0, stream>>>(
        sw1, sw2, sb2, gw1, gw2, fw1, fw2, fw3, filters, enc_glob,
        sw2p, sw1p, gw1p, gw2p, fw1bp, fw2p, sb2p, fw1sp, fw3p, filtp,
        glob_gh, glob_f1);
    k_mfma<<<N_ * (P_ / 256), 512, 0, stream>>>(
        points, transform, sb1, gb1, gb2, fb1, fb2, fb3,
        sw1p, gw1p, sw2p, sb2p, gw2p, fw1bp, fw2p, fw1sp, fw3p, filtp,
        glob_gh, glob_f1, out);
    k_norm<<<N_, 1024, 0, stream>>>(out);
}